// Round 5
// baseline (318.091 us; speedup 1.0000x reference)
//
#include <hip/hip_runtime.h>

// E^H D E exact NDFT as two complex fp16 MFMA GEMMs (fp32 accumulate).
// R5 = R3's proven math (fwd/adj inner loops identical) + two isolated fixes:
//   (1) adj split-K partials written COALESCED as P[sp][t][y][x] + transpose-combine
//   (2) ASPLIT 4 -> 8
// This bisects R4's validation failure (which changed fwd+adj tilings at once).

#define NT 16
#define NK 2048
#define NXY 128
#define NC 8
#define ASPLIT 8

typedef _Float16 f16x8 __attribute__((ext_vector_type(8)));
typedef float f32x4 __attribute__((ext_vector_type(4)));

union F8 { f16x8 h; uint u[4]; uint4 q; };

#define MFMA16(a, b, c) __builtin_amdgcn_mfma_f32_16x16x32_f16((a), (b), (c), 0, 0, 0)

__device__ __forceinline__ uint pack2h(float a, float b) {
    union { _Float16 h[2]; uint u; } p;
    p.h[0] = (_Float16)a; p.h[1] = (_Float16)b;
    return p.u;
}
__device__ __forceinline__ float2 unpack2h(uint v) {
    union { uint u; _Float16 h[2]; } p;
    p.u = v;
    return make_float2((float)p.h[0], (float)p.h[1]);
}
__device__ __forceinline__ uint rot16(uint v) { return (v >> 16) | (v << 16); }

// ---------------------------------------------------------------------------
// kt2[p][t][k] = ktraj[p][k][t]; dcT[t][k] = dcomp[k][t]
// ---------------------------------------------------------------------------
__global__ __launch_bounds__(256) void meta_t(const float* __restrict__ ktraj,
                                              const float* __restrict__ dcomp,
                                              float* __restrict__ kt2,
                                              float* __restrict__ dcT) {
    const int row = blockIdx.x, p = row >> 4, t = row & 15;
    const float* src = (p < 2) ? (ktraj + (size_t)p * NK * NT) : dcomp;
    float* dst = (p < 2) ? (kt2 + ((size_t)p * NT + t) * NK) : (dcT + (size_t)t * NK);
    for (int k = threadIdx.x; k < NK; k += 256) dst[k] = src[(size_t)k * NT + t];
}

// ---------------------------------------------------------------------------
// ExT[t][x][k], EyT[t][y][k]: exp(-i*k_{x|y}*(pos-64)) packed fp16. k in lanes.
// ---------------------------------------------------------------------------
__global__ __launch_bounds__(256) void prep_xmajor(const float* __restrict__ kt2,
                                                   uint* __restrict__ ExT,
                                                   uint* __restrict__ EyT) {
    const size_t idx = (size_t)blockIdx.x * 256 + threadIdx.x;  // [t][x][k]
    const int k = idx & (NK - 1);
    const int x = (idx >> 11) & (NXY - 1);
    const int t = (int)(idx >> 18);
    const float kx = kt2[(size_t)t * NK + k];
    const float ky = kt2[(size_t)(NT + t) * NK + k];
    const float fx = (float)(64 - x);
    float s, c;
    __sincosf(kx * fx, &s, &c);
    ExT[idx] = pack2h(c, s);
    __sincosf(ky * fx, &s, &c);
    EyT[idx] = pack2h(c, s);
}

// ---------------------------------------------------------------------------
// ExC[t][k][x]: same Ex values, x fastest (for fwd B-fragments).
// ---------------------------------------------------------------------------
__global__ __launch_bounds__(256) void prep_kmajor(const float* __restrict__ kt2,
                                                   uint* __restrict__ ExC) {
    const size_t idx = (size_t)blockIdx.x * 256 + threadIdx.x;  // [t][k][x]
    const int x = idx & (NXY - 1);
    const int k = (idx >> 7) & (NK - 1);
    const int t = (int)(idx >> 18);
    const float kx = kt2[(size_t)t * NK + k];
    float s, c;
    __sincosf(kx * (float)(64 - x), &s, &c);
    ExC[idx] = pack2h(c, s);
}

// ---------------------------------------------------------------------------
// srcB[t][c][y][x] = smap*img packed complex fp16
// ---------------------------------------------------------------------------
__global__ __launch_bounds__(256) void prep_src(const float* __restrict__ xin,
                                                const float* __restrict__ csmap,
                                                uint* __restrict__ srcB) {
    const int idx = blockIdx.x * 256 + threadIdx.x;
    const int x = idx & 127, y = (idx >> 7) & 127, c = (idx >> 14) & 7, t = idx >> 17;
    const float ir = xin[(size_t)(x * NXY + y) * NT + t];
    const float ii = xin[(size_t)NXY * NXY * NT + (size_t)(x * NXY + y) * NT + t];
    const float sr = csmap[(size_t)c * 2 * NXY * NXY + x * NXY + y];
    const float si = csmap[(size_t)c * 2 * NXY * NXY + NXY * NXY + x * NXY + y];
    srcB[(size_t)((t * NC + c) * NXY + y) * NXY + x] =
        pack2h(sr * ir - si * ii, sr * ii + si * ir);
}

// ---------------------------------------------------------------------------
// fwd_gemm (R3-proven, unchanged): block=(t,c,kt of 128), 256 thr.
// C1[y=128, kp=128] over K'=256 halves (x), chunks of 32 halves.
// Epilogue: kdat[kp]=sum_y Ey[kp,y]C1[y,kp]; g[t][c][kp] = kdat*dcomp/16384.
// ---------------------------------------------------------------------------
__global__ __launch_bounds__(256) void fwd_gemm(const uint* __restrict__ ExC,
                                                const uint* __restrict__ EyT,
                                                const uint* __restrict__ srcB,
                                                const float* __restrict__ dcT,
                                                float2* __restrict__ g) {
    const int t = blockIdx.x, c = blockIdx.y, kt = blockIdx.z;
    const int tid = threadIdx.x, lane = tid & 63, wv = tid >> 6;
    const int quad = lane >> 4, l15 = lane & 15;

    __shared__ __align__(16) _Float16 As[2][128][40];

    f32x4 accr[8][2], acci[8][2];
#pragma unroll
    for (int mf = 0; mf < 8; ++mf)
#pragma unroll
        for (int nf = 0; nf < 2; ++nf) {
            accr[mf][nf] = (f32x4)0.0f;
            acci[mf][nf] = (f32x4)0.0f;
        }

    const uint* srcRow = srcB + (size_t)((t * NC + c) * NXY) * NXY;
    const uint* exRow  = ExC + ((size_t)t * NK + kt * 128) * NXY;

#pragma unroll
    for (int p = 0; p < 2; ++p) {
        int lin = p * 256 + tid, y = lin >> 2, xi = lin & 3;
        F8 v; v.q = *(const uint4*)(srcRow + y * NXY + xi * 4);
        *(F8*)&As[0][y][xi * 8] = v;
    }
    __syncthreads();

    for (int ch = 0; ch < 8; ++ch) {
        const int buf = ch & 1;
        F8 Bf[2];
#pragma unroll
        for (int nf = 0; nf < 2; ++nf) {
            int kp_local = wv * 32 + nf * 16 + l15;
            Bf[nf].q = *(const uint4*)(exRow + kp_local * NXY + ch * 16 + quad * 4);
        }
#pragma unroll
        for (int mf = 0; mf < 8; ++mf) {
            F8 Ap = *(const F8*)&As[buf][mf * 16 + l15][quad * 8];
            F8 Ar, Ai;
#pragma unroll
            for (int d = 0; d < 4; ++d) {
                Ar.u[d] = Ap.u[d] ^ 0x80000000u;   // (sR, -sI)
                Ai.u[d] = rot16(Ap.u[d]);          // (sI,  sR)
            }
#pragma unroll
            for (int nf = 0; nf < 2; ++nf) {
                accr[mf][nf] = MFMA16(Ar.h, Bf[nf].h, accr[mf][nf]);
                acci[mf][nf] = MFMA16(Ai.h, Bf[nf].h, acci[mf][nf]);
            }
        }
        if (ch < 7) {
#pragma unroll
            for (int p = 0; p < 2; ++p) {
                int lin = p * 256 + tid, y = lin >> 2, xi = lin & 3;
                F8 v; v.q = *(const uint4*)(srcRow + y * NXY + (ch + 1) * 16 + xi * 4);
                *(F8*)&As[buf ^ 1][y][xi * 8] = v;
            }
        }
        __syncthreads();
    }

    const uint* eyT = EyT + (size_t)t * NXY * NK;
#pragma unroll
    for (int nf = 0; nf < 2; ++nf) {
        const int kpoint = kt * 128 + wv * 32 + nf * 16 + l15;
        float kdr = 0.f, kdi = 0.f;
#pragma unroll
        for (int mf = 0; mf < 8; ++mf) {
#pragma unroll
            for (int r = 0; r < 4; ++r) {
                const int y = mf * 16 + quad * 4 + r;
                float2 ey = unpack2h(eyT[(size_t)y * NK + kpoint]);
                float cr = accr[mf][nf][r], ci = acci[mf][nf][r];
                kdr += ey.x * cr - ey.y * ci;
                kdi += ey.x * ci + ey.y * cr;
            }
        }
        kdr += __shfl_xor(kdr, 16); kdr += __shfl_xor(kdr, 32);
        kdi += __shfl_xor(kdi, 16); kdi += __shfl_xor(kdi, 32);
        if (lane < 16) {
            float w = dcT[(size_t)t * NK + kpoint] * (1.0f / 16384.0f);
            g[((size_t)t * NC + c) * NK + kpoint] = make_float2(kdr * w, kdi * w);
        }
    }
}

// ---------------------------------------------------------------------------
// adj_gemm (R3-proven inner loop): block=(t, yt of 8 y, sp of 256 kp), 512 thr.
// C3[m=(yloc*8+c)=64, x=128] over K'=512 halves, chunks of 32 kpts.
// Ts XOR-swizzled. Epilogue: coil-combine -> COALESCED P[sp][t][y][x]  (R5 fix)
// ---------------------------------------------------------------------------
__global__ __launch_bounds__(512) void adj_gemm(const uint* __restrict__ ExT,
                                                const uint* __restrict__ EyT,
                                                const float2* __restrict__ g,
                                                const float* __restrict__ csmap,
                                                float2* __restrict__ P) {
    const int t = blockIdx.x, yt = blockIdx.y, sp = blockIdx.z;
    const int ybase = yt * 8;
    const int kbase = sp * (NK / ASPLIT);
    const int tid = threadIdx.x, lane = tid & 63;
    const int wv = tid >> 6, quad = lane >> 4, l15 = lane & 15;
    const int x = wv * 16 + l15;

    __shared__ __align__(16) _Float16 Ts[2][64][72];

    f32x4 accr[4], acci[4];
#pragma unroll
    for (int mf = 0; mf < 4; ++mf) { accr[mf] = (f32x4)0.0f; acci[mf] = (f32x4)0.0f; }

    const uint* exB = ExT + ((size_t)t * NXY + x) * NK;

    const int bm = tid & 63, bslot = tid >> 6;
    const int bk4 = bslot * 4;
    const int by = ybase + (bm >> 3), bc = bm & 7;
    const float2* gc = g + ((size_t)t * NC + bc) * NK;
    const uint* eyr = EyT + ((size_t)t * NXY + by) * NK;
    const int bphys = (bslot ^ ((bm >> 3) & 3)) * 8;

    auto build = [&](int ch, int buf) {
        const int kp0 = kbase + ch * 32 + bk4;
        float4 ga = *(const float4*)(gc + kp0);
        float4 gb = *(const float4*)(gc + kp0 + 2);
        uint4 e4 = *(const uint4*)(eyr + kp0);
        float2 e0 = unpack2h(e4.x), e1 = unpack2h(e4.y);
        float2 e2 = unpack2h(e4.z), e3 = unpack2h(e4.w);
        F8 w;
        w.u[0] = pack2h(e0.x * ga.x + e0.y * ga.y, e0.x * ga.y - e0.y * ga.x);
        w.u[1] = pack2h(e1.x * ga.z + e1.y * ga.w, e1.x * ga.w - e1.y * ga.z);
        w.u[2] = pack2h(e2.x * gb.x + e2.y * gb.y, e2.x * gb.y - e2.y * gb.x);
        w.u[3] = pack2h(e3.x * gb.z + e3.y * gb.w, e3.x * gb.w - e3.y * gb.z);
        *(F8*)&Ts[buf][bm][bphys] = w;
    };

    build(0, 0);
    __syncthreads();

    const int NCH = (NK / ASPLIT) / 32;   // 8
    for (int ch = 0; ch < NCH; ++ch) {
        const int buf = ch & 1;
#pragma unroll
        for (int ks = 0; ks < 2; ++ks) {
            const int kp = kbase + ch * 32 + ks * 16 + quad * 4;
            F8 Bf; Bf.q = *(const uint4*)(exB + kp);
#pragma unroll
            for (int mf = 0; mf < 4; ++mf) {
                const int row = mf * 16 + l15;
                const int phys = ((ks * 4 + quad) ^ ((row >> 3) & 3)) * 8;
                F8 Ap = *(const F8*)&Ts[buf][row][phys];
                F8 Ai;
#pragma unroll
                for (int d = 0; d < 4; ++d) Ai.u[d] = rot16(Ap.u[d]) ^ 0x80000000u;
                accr[mf] = MFMA16(Ap.h, Bf.h, accr[mf]);
                acci[mf] = MFMA16(Ai.h, Bf.h, acci[mf]);
            }
        }
        if (ch < NCH - 1) build(ch + 1, buf ^ 1);
        __syncthreads();
    }

    // epilogue: coil-combine with conj(smap) -> P[sp][t][y][x] (coalesced in x)
#pragma unroll
    for (int mf = 0; mf < 4; ++mf) {
        const int y = ybase + 2 * mf + (quad >> 1);
        float or_ = 0.f, oi_ = 0.f;
#pragma unroll
        for (int r = 0; r < 4; ++r) {
            int c = 4 * (quad & 1) + r;
            float sr = csmap[(size_t)c * 2 * NXY * NXY + x * NXY + y];
            float si = csmap[(size_t)c * 2 * NXY * NXY + NXY * NXY + x * NXY + y];
            float xr = accr[mf][r], xi = acci[mf][r];
            or_ += sr * xr + si * xi;
            oi_ += sr * xi - si * xr;
        }
        or_ += __shfl_xor(or_, 16);
        oi_ += __shfl_xor(oi_, 16);
        if ((lane & 16) == 0)
            P[((size_t)(sp * NT + t) * NXY + y) * NXY + x] = make_float2(or_, oi_);
    }
}

// ---------------------------------------------------------------------------
// combine: out[p][x][y][t] = sum_sp P[sp][t][y][x].p — LDS transpose so both
// P reads (x-fastest) and out writes (t-fastest) are coalesced.
// ---------------------------------------------------------------------------
__global__ __launch_bounds__(256) void combine(const float2* __restrict__ P,
                                               float* __restrict__ out) {
    const int y = blockIdx.x, xb = blockIdx.y * 16;
    const int tid = threadIdx.x;
    __shared__ float2 tile[16][17];
    {
        const int xl = tid & 15, tt = tid >> 4;
        float2 s = make_float2(0.f, 0.f);
#pragma unroll
        for (int sp = 0; sp < ASPLIT; ++sp) {
            float2 v = P[((size_t)(sp * NT + tt) * NXY + y) * NXY + xb + xl];
            s.x += v.x; s.y += v.y;
        }
        tile[tt][xl] = s;
    }
    __syncthreads();
    {
        const int tt = tid & 15, xl = tid >> 4;
        float2 v = tile[tt][xl];
        const int x = xb + xl;
        out[((size_t)x * NXY + y) * NT + tt] = v.x;
        out[(size_t)NXY * NXY * NT + ((size_t)x * NXY + y) * NT + tt] = v.y;
    }
}

// ---------------------------------------------------------------------------
extern "C" void kernel_launch(void* const* d_in, const int* in_sizes, int n_in,
                              void* d_out, int out_size, void* d_ws, size_t ws_size,
                              hipStream_t stream) {
    const float* xin   = (const float*)d_in[0];
    const float* ktraj = (const float*)d_in[1];
    const float* csmap = (const float*)d_in[2];
    const float* dcomp = (const float*)d_in[3];
    float* out = (float*)d_out;

    const size_t TBL = (size_t)NT * NK * NXY;        // 4,194,304 dwords
    float* kt2 = (float*)d_ws;                       // [2][t][k]
    float* dcT = kt2 + (size_t)2 * NT * NK;          // [t][k]
    uint* ExC  = (uint*)(dcT + (size_t)NT * NK);     // [t][k][x]
    uint* ExT  = ExC + TBL;                          // [t][x][k]
    uint* EyT  = ExT + TBL;                          // [t][y][k]
    uint* srcB = EyT + TBL;                          // [t][c][y][x]
    float2* g  = (float2*)(srcB + (size_t)NT * NC * NXY * NXY);  // [t][c][k]
    float2* P  = (float2*)ExC;   // partials alias ExC (dead after fwd_gemm);
                                 // ASPLIT*NT*NXY*NXY float2 == TBL dwords exactly

    meta_t<<<3 * NT, 256, 0, stream>>>(ktraj, dcomp, kt2, dcT);
    prep_xmajor<<<(int)(TBL / 256), 256, 0, stream>>>(kt2, ExT, EyT);
    prep_kmajor<<<(int)(TBL / 256), 256, 0, stream>>>(kt2, ExC);
    prep_src<<<(NT * NC * NXY * NXY) / 256, 256, 0, stream>>>(xin, csmap, srcB);
    fwd_gemm<<<dim3(NT, NC, NK / 128), 256, 0, stream>>>(ExC, EyT, srcB, dcT, g);
    adj_gemm<<<dim3(NT, NXY / 8, ASPLIT), 512, 0, stream>>>(ExT, EyT, g, csmap, P);
    combine<<<dim3(NXY, NXY / 16), 256, 0, stream>>>(P, out);
}

// Round 6
// 283.569 us; speedup vs baseline: 1.1217x; 1.1217x over previous
//
#include <hip/hip_runtime.h>

// E^H D E exact NDFT as two complex fp16 MFMA GEMMs (fp32 accumulate).
// R6 = R5's proven math with SOFTWARE PIPELINING only (no math/layout changes):
//   - fwd: next-chunk A-stage + B-frag global loads issued BEFORE the MFMA loop
//   - adj: next-chunk g/Ey loads issued BEFORE the MFMA loop; pack+write after
//   - ASPLIT 8 -> 4 (1024 blocks = 4/CU, 16 chunks/block re-amortizes barriers)
// Rationale: R5 counters showed MfmaUtil 10% / VALUBusy 26% / HBM 3.5% / tiny
// bank conflicts => barrier-drain latency (loads issued after MFMAs, then
// s_waitcnt vmcnt(0) at __syncthreads). Give loads the MFMA shadow.

#define NT 16
#define NK 2048
#define NXY 128
#define NC 8
#define ASPLIT 4

typedef _Float16 f16x8 __attribute__((ext_vector_type(8)));
typedef float f32x4 __attribute__((ext_vector_type(4)));

union F8 { f16x8 h; uint u[4]; uint4 q; };

#define MFMA16(a, b, c) __builtin_amdgcn_mfma_f32_16x16x32_f16((a), (b), (c), 0, 0, 0)

__device__ __forceinline__ uint pack2h(float a, float b) {
    union { _Float16 h[2]; uint u; } p;
    p.h[0] = (_Float16)a; p.h[1] = (_Float16)b;
    return p.u;
}
__device__ __forceinline__ float2 unpack2h(uint v) {
    union { uint u; _Float16 h[2]; } p;
    p.u = v;
    return make_float2((float)p.h[0], (float)p.h[1]);
}
__device__ __forceinline__ uint rot16(uint v) { return (v >> 16) | (v << 16); }

// ---------------------------------------------------------------------------
// kt2[p][t][k] = ktraj[p][k][t]; dcT[t][k] = dcomp[k][t]
// ---------------------------------------------------------------------------
__global__ __launch_bounds__(256) void meta_t(const float* __restrict__ ktraj,
                                              const float* __restrict__ dcomp,
                                              float* __restrict__ kt2,
                                              float* __restrict__ dcT) {
    const int row = blockIdx.x, p = row >> 4, t = row & 15;
    const float* src = (p < 2) ? (ktraj + (size_t)p * NK * NT) : dcomp;
    float* dst = (p < 2) ? (kt2 + ((size_t)p * NT + t) * NK) : (dcT + (size_t)t * NK);
    for (int k = threadIdx.x; k < NK; k += 256) dst[k] = src[(size_t)k * NT + t];
}

// ---------------------------------------------------------------------------
// ExT[t][x][k], EyT[t][y][k]: exp(-i*k_{x|y}*(pos-64)) packed fp16. k in lanes.
// ---------------------------------------------------------------------------
__global__ __launch_bounds__(256) void prep_xmajor(const float* __restrict__ kt2,
                                                   uint* __restrict__ ExT,
                                                   uint* __restrict__ EyT) {
    const size_t idx = (size_t)blockIdx.x * 256 + threadIdx.x;  // [t][x][k]
    const int k = idx & (NK - 1);
    const int x = (idx >> 11) & (NXY - 1);
    const int t = (int)(idx >> 18);
    const float kx = kt2[(size_t)t * NK + k];
    const float ky = kt2[(size_t)(NT + t) * NK + k];
    const float fx = (float)(64 - x);
    float s, c;
    __sincosf(kx * fx, &s, &c);
    ExT[idx] = pack2h(c, s);
    __sincosf(ky * fx, &s, &c);
    EyT[idx] = pack2h(c, s);
}

// ---------------------------------------------------------------------------
// ExC[t][k][x]: same Ex values, x fastest (for fwd B-fragments).
// ---------------------------------------------------------------------------
__global__ __launch_bounds__(256) void prep_kmajor(const float* __restrict__ kt2,
                                                   uint* __restrict__ ExC) {
    const size_t idx = (size_t)blockIdx.x * 256 + threadIdx.x;  // [t][k][x]
    const int x = idx & (NXY - 1);
    const int k = (idx >> 7) & (NK - 1);
    const int t = (int)(idx >> 18);
    const float kx = kt2[(size_t)t * NK + k];
    float s, c;
    __sincosf(kx * (float)(64 - x), &s, &c);
    ExC[idx] = pack2h(c, s);
}

// ---------------------------------------------------------------------------
// srcB[t][c][y][x] = smap*img packed complex fp16
// ---------------------------------------------------------------------------
__global__ __launch_bounds__(256) void prep_src(const float* __restrict__ xin,
                                                const float* __restrict__ csmap,
                                                uint* __restrict__ srcB) {
    const int idx = blockIdx.x * 256 + threadIdx.x;
    const int x = idx & 127, y = (idx >> 7) & 127, c = (idx >> 14) & 7, t = idx >> 17;
    const float ir = xin[(size_t)(x * NXY + y) * NT + t];
    const float ii = xin[(size_t)NXY * NXY * NT + (size_t)(x * NXY + y) * NT + t];
    const float sr = csmap[(size_t)c * 2 * NXY * NXY + x * NXY + y];
    const float si = csmap[(size_t)c * 2 * NXY * NXY + NXY * NXY + x * NXY + y];
    srcB[(size_t)((t * NC + c) * NXY + y) * NXY + x] =
        pack2h(sr * ir - si * ii, sr * ii + si * ir);
}

// ---------------------------------------------------------------------------
// fwd_gemm: block=(t,c,kt of 128), 256 thr. C1[y=128, kp=128] over K'=256
// halves (x), chunks of 32 halves. R6: pipelined (A+B prefetch before MFMAs).
// Epilogue: kdat[kp]=sum_y Ey[kp,y]C1[y,kp]; g[t][c][kp] = kdat*dcomp/16384.
// ---------------------------------------------------------------------------
__global__ __launch_bounds__(256) void fwd_gemm(const uint* __restrict__ ExC,
                                                const uint* __restrict__ EyT,
                                                const uint* __restrict__ srcB,
                                                const float* __restrict__ dcT,
                                                float2* __restrict__ g) {
    const int t = blockIdx.x, c = blockIdx.y, kt = blockIdx.z;
    const int tid = threadIdx.x, lane = tid & 63, wv = tid >> 6;
    const int quad = lane >> 4, l15 = lane & 15;

    __shared__ __align__(16) _Float16 As[2][128][40];

    f32x4 accr[8][2], acci[8][2];
#pragma unroll
    for (int mf = 0; mf < 8; ++mf)
#pragma unroll
        for (int nf = 0; nf < 2; ++nf) {
            accr[mf][nf] = (f32x4)0.0f;
            acci[mf][nf] = (f32x4)0.0f;
        }

    const uint* srcRow = srcB + (size_t)((t * NC + c) * NXY) * NXY;
    const uint* exRow  = ExC + ((size_t)t * NK + kt * 128) * NXY;

    const int ar0 = tid >> 2, ar1 = 64 + (tid >> 2), aq = tid & 3;

    uint4 av0, av1;
    F8 Bcur[2], Bnxt[2];

    // prologue: chunk-0 A stage + B frags
    av0 = *(const uint4*)(srcRow + ar0 * NXY + aq * 4);
    av1 = *(const uint4*)(srcRow + ar1 * NXY + aq * 4);
    Bcur[0].q = *(const uint4*)(exRow + (wv * 32 + l15) * NXY + quad * 4);
    Bcur[1].q = *(const uint4*)(exRow + (wv * 32 + 16 + l15) * NXY + quad * 4);
    *(uint4*)&As[0][ar0][aq * 8] = av0;
    *(uint4*)&As[0][ar1][aq * 8] = av1;
    __syncthreads();

    for (int ch = 0; ch < 8; ++ch) {
        const int buf = ch & 1;
        // issue next-chunk loads EARLY (covered by this chunk's MFMAs)
        if (ch < 7) {
            av0 = *(const uint4*)(srcRow + ar0 * NXY + (ch + 1) * 16 + aq * 4);
            av1 = *(const uint4*)(srcRow + ar1 * NXY + (ch + 1) * 16 + aq * 4);
            Bnxt[0].q = *(const uint4*)(exRow + (wv * 32 + l15) * NXY + (ch + 1) * 16 + quad * 4);
            Bnxt[1].q = *(const uint4*)(exRow + (wv * 32 + 16 + l15) * NXY + (ch + 1) * 16 + quad * 4);
        }
#pragma unroll
        for (int mf = 0; mf < 8; ++mf) {
            F8 Ap = *(const F8*)&As[buf][mf * 16 + l15][quad * 8];
            F8 Ar, Ai;
#pragma unroll
            for (int d = 0; d < 4; ++d) {
                Ar.u[d] = Ap.u[d] ^ 0x80000000u;   // (sR, -sI)
                Ai.u[d] = rot16(Ap.u[d]);          // (sI,  sR)
            }
            accr[mf][0] = MFMA16(Ar.h, Bcur[0].h, accr[mf][0]);
            acci[mf][0] = MFMA16(Ai.h, Bcur[0].h, acci[mf][0]);
            accr[mf][1] = MFMA16(Ar.h, Bcur[1].h, accr[mf][1]);
            acci[mf][1] = MFMA16(Ai.h, Bcur[1].h, acci[mf][1]);
        }
        if (ch < 7) {
            *(uint4*)&As[buf ^ 1][ar0][aq * 8] = av0;
            *(uint4*)&As[buf ^ 1][ar1][aq * 8] = av1;
        }
        __syncthreads();
        Bcur[0] = Bnxt[0];
        Bcur[1] = Bnxt[1];
    }

    const uint* eyT = EyT + (size_t)t * NXY * NK;
#pragma unroll
    for (int nf = 0; nf < 2; ++nf) {
        const int kpoint = kt * 128 + wv * 32 + nf * 16 + l15;
        float kdr = 0.f, kdi = 0.f;
#pragma unroll
        for (int mf = 0; mf < 8; ++mf) {
#pragma unroll
            for (int r = 0; r < 4; ++r) {
                const int y = mf * 16 + quad * 4 + r;
                float2 ey = unpack2h(eyT[(size_t)y * NK + kpoint]);
                float cr = accr[mf][nf][r], ci = acci[mf][nf][r];
                kdr += ey.x * cr - ey.y * ci;
                kdi += ey.x * ci + ey.y * cr;
            }
        }
        kdr += __shfl_xor(kdr, 16); kdr += __shfl_xor(kdr, 32);
        kdi += __shfl_xor(kdi, 16); kdi += __shfl_xor(kdi, 32);
        if (lane < 16) {
            float w = dcT[(size_t)t * NK + kpoint] * (1.0f / 16384.0f);
            g[((size_t)t * NC + c) * NK + kpoint] = make_float2(kdr * w, kdi * w);
        }
    }
}

// ---------------------------------------------------------------------------
// adj_gemm: block=(t, yt of 8 y, sp of 512 kp), 512 thr. ASPLIT=4, NCH=16.
// C3[m=(yloc*8+c)=64, x=128] over K'=1024 halves, chunks of 32 kpts.
// R6: g/Ey loads for chunk ch+1 issued BEFORE chunk ch's MFMA loop.
// Epilogue: coil-combine -> coalesced P[sp][t][y][x].
// ---------------------------------------------------------------------------
__global__ __launch_bounds__(512) void adj_gemm(const uint* __restrict__ ExT,
                                                const uint* __restrict__ EyT,
                                                const float2* __restrict__ g,
                                                const float* __restrict__ csmap,
                                                float2* __restrict__ P) {
    const int t = blockIdx.x, yt = blockIdx.y, sp = blockIdx.z;
    const int ybase = yt * 8;
    const int kbase = sp * (NK / ASPLIT);
    const int tid = threadIdx.x, lane = tid & 63;
    const int wv = tid >> 6, quad = lane >> 4, l15 = lane & 15;
    const int x = wv * 16 + l15;

    __shared__ __align__(16) _Float16 Ts[2][64][72];

    f32x4 accr[4], acci[4];
#pragma unroll
    for (int mf = 0; mf < 4; ++mf) { accr[mf] = (f32x4)0.0f; acci[mf] = (f32x4)0.0f; }

    const uint* exB = ExT + ((size_t)t * NXY + x) * NK;

    const int bm = tid & 63, bslot = tid >> 6;
    const int bk4 = bslot * 4;
    const int by = ybase + (bm >> 3), bc = bm & 7;
    const float2* gc = g + ((size_t)t * NC + bc) * NK;
    const uint* eyr = EyT + ((size_t)t * NXY + by) * NK;
    const int bphys = (bslot ^ ((bm >> 3) & 3)) * 8;

    float4 ga, gb;   // prefetched g (4 kp)
    uint4 e4;        // prefetched Ey (4 kp)

    auto loadG = [&](int ch) {
        const int kp0 = kbase + ch * 32 + bk4;
        ga = *(const float4*)(gc + kp0);
        gb = *(const float4*)(gc + kp0 + 2);
        e4 = *(const uint4*)(eyr + kp0);
    };
    auto packWrite = [&](int buf) {
        float2 e0 = unpack2h(e4.x), e1 = unpack2h(e4.y);
        float2 e2 = unpack2h(e4.z), e3 = unpack2h(e4.w);
        F8 w;
        w.u[0] = pack2h(e0.x * ga.x + e0.y * ga.y, e0.x * ga.y - e0.y * ga.x);
        w.u[1] = pack2h(e1.x * ga.z + e1.y * ga.w, e1.x * ga.w - e1.y * ga.z);
        w.u[2] = pack2h(e2.x * gb.x + e2.y * gb.y, e2.x * gb.y - e2.y * gb.x);
        w.u[3] = pack2h(e3.x * gb.z + e3.y * gb.w, e3.x * gb.w - e3.y * gb.z);
        *(F8*)&Ts[buf][bm][bphys] = w;
    };

    loadG(0);
    packWrite(0);
    __syncthreads();

    const int NCH = (NK / ASPLIT) / 32;   // 16
    for (int ch = 0; ch < NCH; ++ch) {
        const int buf = ch & 1;
        if (ch < NCH - 1) loadG(ch + 1);   // issue EARLY (MFMA shadow)
#pragma unroll
        for (int ks = 0; ks < 2; ++ks) {
            const int kp = kbase + ch * 32 + ks * 16 + quad * 4;
            F8 Bf; Bf.q = *(const uint4*)(exB + kp);
#pragma unroll
            for (int mf = 0; mf < 4; ++mf) {
                const int row = mf * 16 + l15;
                const int phys = ((ks * 4 + quad) ^ ((row >> 3) & 3)) * 8;
                F8 Ap = *(const F8*)&Ts[buf][row][phys];
                F8 Ai;
#pragma unroll
                for (int d = 0; d < 4; ++d) Ai.u[d] = rot16(Ap.u[d]) ^ 0x80000000u;
                accr[mf] = MFMA16(Ap.h, Bf.h, accr[mf]);
                acci[mf] = MFMA16(Ai.h, Bf.h, acci[mf]);
            }
        }
        if (ch < NCH - 1) packWrite(buf ^ 1);
        __syncthreads();
    }

    // epilogue: coil-combine with conj(smap) -> P[sp][t][y][x] (coalesced in x)
#pragma unroll
    for (int mf = 0; mf < 4; ++mf) {
        const int y = ybase + 2 * mf + (quad >> 1);
        float or_ = 0.f, oi_ = 0.f;
#pragma unroll
        for (int r = 0; r < 4; ++r) {
            int c = 4 * (quad & 1) + r;
            float sr = csmap[(size_t)c * 2 * NXY * NXY + x * NXY + y];
            float si = csmap[(size_t)c * 2 * NXY * NXY + NXY * NXY + x * NXY + y];
            float xr = accr[mf][r], xi = acci[mf][r];
            or_ += sr * xr + si * xi;
            oi_ += sr * xi - si * xr;
        }
        or_ += __shfl_xor(or_, 16);
        oi_ += __shfl_xor(oi_, 16);
        if ((lane & 16) == 0)
            P[((size_t)(sp * NT + t) * NXY + y) * NXY + x] = make_float2(or_, oi_);
    }
}

// ---------------------------------------------------------------------------
// combine: out[p][x][y][t] = sum_sp P[sp][t][y][x].p — LDS transpose so both
// P reads (x-fastest) and out writes (t-fastest) are coalesced.
// ---------------------------------------------------------------------------
__global__ __launch_bounds__(256) void combine(const float2* __restrict__ P,
                                               float* __restrict__ out) {
    const int y = blockIdx.x, xb = blockIdx.y * 16;
    const int tid = threadIdx.x;
    __shared__ float2 tile[16][17];
    {
        const int xl = tid & 15, tt = tid >> 4;
        float2 s = make_float2(0.f, 0.f);
#pragma unroll
        for (int sp = 0; sp < ASPLIT; ++sp) {
            float2 v = P[((size_t)(sp * NT + tt) * NXY + y) * NXY + xb + xl];
            s.x += v.x; s.y += v.y;
        }
        tile[tt][xl] = s;
    }
    __syncthreads();
    {
        const int tt = tid & 15, xl = tid >> 4;
        float2 v = tile[tt][xl];
        const int x = xb + xl;
        out[((size_t)x * NXY + y) * NT + tt] = v.x;
        out[(size_t)NXY * NXY * NT + ((size_t)x * NXY + y) * NT + tt] = v.y;
    }
}

// ---------------------------------------------------------------------------
extern "C" void kernel_launch(void* const* d_in, const int* in_sizes, int n_in,
                              void* d_out, int out_size, void* d_ws, size_t ws_size,
                              hipStream_t stream) {
    const float* xin   = (const float*)d_in[0];
    const float* ktraj = (const float*)d_in[1];
    const float* csmap = (const float*)d_in[2];
    const float* dcomp = (const float*)d_in[3];
    float* out = (float*)d_out;

    const size_t TBL = (size_t)NT * NK * NXY;        // 4,194,304 dwords
    float* kt2 = (float*)d_ws;                       // [2][t][k]
    float* dcT = kt2 + (size_t)2 * NT * NK;          // [t][k]
    uint* ExC  = (uint*)(dcT + (size_t)NT * NK);     // [t][k][x]
    uint* ExT  = ExC + TBL;                          // [t][x][k]
    uint* EyT  = ExT + TBL;                          // [t][y][k]
    uint* srcB = EyT + TBL;                          // [t][c][y][x]
    float2* g  = (float2*)(srcB + (size_t)NT * NC * NXY * NXY);  // [t][c][k]
    float2* P  = (float2*)ExC;   // partials alias ExC (dead after fwd_gemm);
                                 // ASPLIT*NT*NXY*NXY float2 = 8.4 MB < TBL dwords

    meta_t<<<3 * NT, 256, 0, stream>>>(ktraj, dcomp, kt2, dcT);
    prep_xmajor<<<(int)(TBL / 256), 256, 0, stream>>>(kt2, ExT, EyT);
    prep_kmajor<<<(int)(TBL / 256), 256, 0, stream>>>(kt2, ExC);
    prep_src<<<(NT * NC * NXY * NXY) / 256, 256, 0, stream>>>(xin, csmap, srcB);
    fwd_gemm<<<dim3(NT, NC, NK / 128), 256, 0, stream>>>(ExC, EyT, srcB, dcT, g);
    adj_gemm<<<dim3(NT, NXY / 8, ASPLIT), 512, 0, stream>>>(ExT, EyT, g, csmap, P);
    combine<<<dim3(NXY, NXY / 16), 256, 0, stream>>>(P, out);
}